// Round 6
// baseline (2026.648 us; speedup 1.0000x reference)
//
#include <hip/hip_runtime.h>
#include <math.h>

#define HWSZ (512*512)

typedef unsigned int u32;
typedef unsigned short u16;
typedef __attribute__((ext_vector_type(8))) short short8;
typedef __attribute__((ext_vector_type(4))) float f32x4;

__device__ __forceinline__ u16 f2bf(float f) {
    unsigned u = __float_as_uint(f);
    unsigned r = (u + 0x7FFFu + ((u >> 16) & 1u)) >> 16;
    return (u16)r;
}
__device__ __forceinline__ float bf2f(u16 h) {
    return __uint_as_float((unsigned)h << 16);
}

// Grid is (8,128). Map so that (assuming round-robin of consecutive linear
// blocks over 8 XCDs, x fastest) XCD k = blockIdx.x owns a contiguous 64-row
// slab: yt = bx*16 + (by>>3), xt = by&7. conv1->conv2->conv3 then reuse the
// same slab in the same XCD's L2.
__device__ __forceinline__ void tile_swizzle(int& xt, int& yt) {
    xt = (int)blockIdx.y & 7;
    yt = (int)blockIdx.x * 16 + ((int)blockIdx.y >> 3);
}

// ---------------------------------------------------------------------------
// Weight prep: fp32 OIHW -> [tap][co][ci] bf16 hi/lo (Markidis split).
// conv2 (64x32), conv3 (32x64), heads packed+padded to 16 co (12 valid).
// ---------------------------------------------------------------------------
__global__ void prep_weights(const float* __restrict__ w2, const float* __restrict__ w3,
                             const float* __restrict__ hw1, const float* __restrict__ hw2,
                             const float* __restrict__ hw3,
                             const float* __restrict__ hb1, const float* __restrict__ hb2,
                             const float* __restrict__ hb3,
                             u16* __restrict__ w2h, u16* __restrict__ w2l,
                             u16* __restrict__ w3h, u16* __restrict__ w3l,
                             u16* __restrict__ whh, u16* __restrict__ whl,
                             float* __restrict__ hb16)
{
    int i = blockIdx.x * 256 + threadIdx.x;
    if (i < 18432) {
        int tap = i / 2048, r = i % 2048, co = r / 32, ci = r % 32;
        float v = w2[((co * 32 + ci) * 9) + tap];
        u16 h = f2bf(v);
        w2h[i] = h; w2l[i] = f2bf(v - bf2f(h));
    } else if (i < 36864) {
        int e = i - 18432;
        int tap = e / 2048, r = e % 2048, co = r / 64, ci = r % 64;
        float v = w3[((co * 64 + ci) * 9) + tap];
        u16 h = f2bf(v);
        w3h[e] = h; w3l[e] = f2bf(v - bf2f(h));
    } else if (i < 41472) {
        int e = i - 36864;
        int tap = e / 512, r = e % 512, co16 = r / 32, ci = r % 32;
        float v = 0.f;
        if (co16 < 12) {
            int hd = co16 >> 2, cl = co16 & 3;
            const float* wp = hd == 0 ? hw1 : (hd == 1 ? hw2 : hw3);
            v = wp[((cl * 32 + ci) * 9) + tap];
        }
        u16 h = f2bf(v);
        whh[e] = h; whl[e] = f2bf(v - bf2f(h));
    } else if (i < 41488) {
        int j = i - 41472;
        float v = 0.f;
        if (j < 12) {
            const float* bp = (j >> 2) == 0 ? hb1 : ((j >> 2) == 1 ? hb2 : hb3);
            v = bp[j & 3];
        }
        hb16[j] = v;
    }
}

// ---------------------------------------------------------------------------
// 3x3 conv + bias + PReLU, channel-last split bf16 hi/lo planes in/out.
// NO LDS, NO barriers: A-fragments load straight from global (L1/L2-hot tap
// re-reads); 3-pass compensated bf16 MFMA 16x16x32.
// Block = 4 waves; wave w owns output row y0+w, 4 col-groups of 16.
// D layout (m89/m91): col(n)=lane&15, row(m)=quad*4+reg. A: m=lane&15, k=quad*8+j.
// ---------------------------------------------------------------------------
template<int CIN, int COUT>
__global__ __launch_bounds__(256)
void conv_mfma(const u16* __restrict__ inh, const u16* __restrict__ inl,
               const u16* __restrict__ wh, const u16* __restrict__ wl,
               const float* __restrict__ bias, const float* __restrict__ alpha,
               u16* __restrict__ outh, u16* __restrict__ outl)
{
    constexpr int NTW = COUT / 16;
    const int tid  = threadIdx.x;
    const int w    = tid >> 6;
    const int lane = tid & 63;
    const int ln   = lane & 15;
    const int quad = lane >> 4;
    int xt, yt; tile_swizzle(xt, yt);
    const int x1  = xt * 64;
    const int row = yt * 4 + w;

    f32x4 acc[4][NTW];
    #pragma unroll
    for (int mt = 0; mt < 4; ++mt)
        #pragma unroll
        for (int nt = 0; nt < NTW; ++nt)
            acc[mt][nt] = (f32x4){0.f, 0.f, 0.f, 0.f};

    const short8 zz = {0, 0, 0, 0, 0, 0, 0, 0};

    #pragma unroll 1
    for (int kk = 0; kk < CIN / 32; ++kk) {
        #pragma unroll
        for (int tap = 0; tap < 9; ++tap) {
            const int dy = tap / 3, dx = tap % 3;
            const int gy = row + dy - 1;
            const bool rowok = (unsigned)gy < 512u;
            const int gyc = min(max(gy, 0), 511);

            short8 bh[NTW], bl[NTW];
            #pragma unroll
            for (int nt = 0; nt < NTW; ++nt) {
                const size_t boff = ((size_t)(tap * COUT + nt * 16 + ln)) * CIN + kk * 32 + quad * 8;
                bh[nt] = *(const short8*)(wh + boff);
                bl[nt] = *(const short8*)(wl + boff);
            }
            short8 ah[4], al[4];
            #pragma unroll
            for (int mt = 0; mt < 4; ++mt) {
                const int gx  = x1 + mt * 16 + ln + dx - 1;
                const bool ok = rowok && ((unsigned)gx < 512u);
                const int gxc = min(max(gx, 0), 511);
                const size_t off = ((size_t)(gyc * 512 + gxc)) * CIN + kk * 32 + quad * 8;
                ah[mt] = ok ? *(const short8*)(inh + off) : zz;
                al[mt] = ok ? *(const short8*)(inl + off) : zz;
            }
            // pass-major: same-acc dependency distance = 4*NTW
            #pragma unroll
            for (int mt = 0; mt < 4; ++mt)
                #pragma unroll
                for (int nt = 0; nt < NTW; ++nt)
                    acc[mt][nt] = __builtin_amdgcn_mfma_f32_16x16x32_bf16(ah[mt], bh[nt], acc[mt][nt], 0, 0, 0);
            #pragma unroll
            for (int mt = 0; mt < 4; ++mt)
                #pragma unroll
                for (int nt = 0; nt < NTW; ++nt)
                    acc[mt][nt] = __builtin_amdgcn_mfma_f32_16x16x32_bf16(al[mt], bh[nt], acc[mt][nt], 0, 0, 0);
            #pragma unroll
            for (int mt = 0; mt < 4; ++mt)
                #pragma unroll
                for (int nt = 0; nt < NTW; ++nt)
                    acc[mt][nt] = __builtin_amdgcn_mfma_f32_16x16x32_bf16(ah[mt], bl[nt], acc[mt][nt], 0, 0, 0);
        }
    }

    // ---- epilogue: bias + PReLU + split-plane stores ----
    const float av = alpha[0];
    #pragma unroll
    for (int nt = 0; nt < NTW; ++nt) {
        const int co = nt * 16 + ln;
        const float bs = bias[co];
        #pragma unroll
        for (int mt = 0; mt < 4; ++mt) {
            const int px0 = row * 512 + x1 + mt * 16 + quad * 4;
            #pragma unroll
            for (int reg = 0; reg < 4; ++reg) {
                float t = acc[mt][nt][reg] + bs;
                t = t > 0.f ? t : av * t;
                u16 h = f2bf(t);
                u16 l = f2bf(t - bf2f(h));
                const size_t o = (size_t)(px0 + reg) * COUT + co;
                outh[o] = h;
                outl[o] = l;
            }
        }
    }
}

// ---------------------------------------------------------------------------
// Head conv: 32 -> 16 co (12 valid = 3 heads x 4), direct-global A, 3-pass
// MFMA + GAP atomics. Writes h planes NCHW fp32 via small LDS transpose.
// ---------------------------------------------------------------------------
__global__ __launch_bounds__(256)
void head_mfma(const u16* __restrict__ inh, const u16* __restrict__ inl,
               const u16* __restrict__ wh, const u16* __restrict__ wl,
               const float* __restrict__ hb,
               float* __restrict__ h, float* __restrict__ g2, int b)
{
    __shared__ float s_h[12 * 260];
    __shared__ float s_red[4][16];

    const int tid  = threadIdx.x;
    const int w    = tid >> 6;
    const int lane = tid & 63;
    const int ln   = lane & 15;
    const int quad = lane >> 4;
    int xt, yt; tile_swizzle(xt, yt);
    const int x1  = xt * 64;
    const int y0  = yt * 4;
    const int row = y0 + w;

    f32x4 acc[4];
    #pragma unroll
    for (int mt = 0; mt < 4; ++mt) acc[mt] = (f32x4){0.f, 0.f, 0.f, 0.f};
    const short8 zz = {0, 0, 0, 0, 0, 0, 0, 0};

    #pragma unroll
    for (int tap = 0; tap < 9; ++tap) {
        const int dy = tap / 3, dx = tap % 3;
        const int gy = row + dy - 1;
        const bool rowok = (unsigned)gy < 512u;
        const int gyc = min(max(gy, 0), 511);
        const size_t boff = (size_t)tap * 512 + ln * 32 + quad * 8;
        short8 bh = *(const short8*)(wh + boff);
        short8 bl = *(const short8*)(wl + boff);
        short8 ah[4], al[4];
        #pragma unroll
        for (int mt = 0; mt < 4; ++mt) {
            const int gx  = x1 + mt * 16 + ln + dx - 1;
            const bool ok = rowok && ((unsigned)gx < 512u);
            const int gxc = min(max(gx, 0), 511);
            const size_t off = ((size_t)(gyc * 512 + gxc)) * 32 + quad * 8;
            ah[mt] = ok ? *(const short8*)(inh + off) : zz;
            al[mt] = ok ? *(const short8*)(inl + off) : zz;
        }
        #pragma unroll
        for (int mt = 0; mt < 4; ++mt)
            acc[mt] = __builtin_amdgcn_mfma_f32_16x16x32_bf16(ah[mt], bh, acc[mt], 0, 0, 0);
        #pragma unroll
        for (int mt = 0; mt < 4; ++mt)
            acc[mt] = __builtin_amdgcn_mfma_f32_16x16x32_bf16(al[mt], bh, acc[mt], 0, 0, 0);
        #pragma unroll
        for (int mt = 0; mt < 4; ++mt)
            acc[mt] = __builtin_amdgcn_mfma_f32_16x16x32_bf16(ah[mt], bl, acc[mt], 0, 0, 0);
    }

    const float bs = hb[ln];
    float psum = 0.f;
    #pragma unroll
    for (int mt = 0; mt < 4; ++mt) {
        const int base = w * 64 + mt * 16 + quad * 4;
        #pragma unroll
        for (int reg = 0; reg < 4; ++reg) {
            float v = acc[mt][reg] + bs;
            if (ln < 12) s_h[ln * 260 + base + reg] = v;
            psum += v;                 // lanes >= 12: zero weights+bias -> 0
        }
    }
    psum += __shfl_down(psum, 16);
    psum += __shfl_down(psum, 32);
    if (lane < 16) s_red[w][lane] = psum;
    __syncthreads();

    if (tid < 192) {
        const int co = tid >> 4, ch = tid & 15;
        const float* src = s_h + co * 260 + ch * 16;
        float4 v0 = *(const float4*)(src);
        float4 v1 = *(const float4*)(src + 4);
        float4 v2 = *(const float4*)(src + 8);
        float4 v3 = *(const float4*)(src + 12);
        const int hd = co >> 2, cl = co & 3;
        float* dst = h + ((size_t)((hd * 8 + b) * 4 + cl)) * HWSZ
                       + (size_t)(y0 + (ch >> 2)) * 512 + x1 + ((ch & 3) << 4);
        *(float4*)(dst)      = v0;
        *(float4*)(dst + 4)  = v1;
        *(float4*)(dst + 8)  = v2;
        *(float4*)(dst + 12) = v3;
    }
    if (tid < 12) {
        float t = s_red[0][tid] + s_red[1][tid] + s_red[2][tid] + s_red[3][tid];
        atomicAdd(&g2[(tid >> 2) * 32 + b * 4 + (tid & 3)], t);
    }
}

// ---------------------------------------------------------------------------
// conv1: 3 -> 32, fp32 direct, thread-per-pixel, writes split hi/lo planes.
// ---------------------------------------------------------------------------
__global__ __launch_bounds__(256)
void conv1_split(const float* __restrict__ x, const float* __restrict__ wgt,
                 const float* __restrict__ bias, const float* __restrict__ alpha,
                 u16* __restrict__ outh, u16* __restrict__ outl)
{
    __shared__ float s_in[3][6][72];
    __shared__ float s_w[3][9][32];
    __shared__ float s_b[32];
    const int tid = threadIdx.x;
    int xt, yt; tile_swizzle(xt, yt);
    const int x1 = xt * 64, y0 = yt * 4;

    for (int i = tid; i < 3 * 6 * 66; i += 256) {
        int ci = i / 396, rm = i % 396;
        int r = rm / 66, cc = rm % 66;
        int gy = y0 - 1 + r, gx = x1 - 1 + cc;
        float v = 0.f;
        if ((unsigned)gy < 512u && (unsigned)gx < 512u)
            v = x[(size_t)ci * HWSZ + gy * 512 + gx];
        s_in[ci][r][cc] = v;
    }
    for (int i = tid; i < 864; i += 256) {
        int co = i & 31, rm = i >> 5;
        int ci = rm / 9, tap = rm % 9;
        s_w[ci][tap][co] = wgt[(co * 3 + ci) * 9 + tap];
    }
    if (tid < 32) s_b[tid] = bias[tid];
    __syncthreads();

    const int ty = tid >> 6, tx = tid & 63;
    float acc[32];
    #pragma unroll
    for (int i = 0; i < 32; ++i) acc[i] = 0.f;
    #pragma unroll
    for (int ci = 0; ci < 3; ++ci)
        #pragma unroll
        for (int tap = 0; tap < 9; ++tap) {
            const int dy = tap / 3, dx = tap % 3;
            float iv = s_in[ci][ty + dy][tx + dx];
            #pragma unroll
            for (int c4 = 0; c4 < 8; ++c4) {
                float4 wv = *(const float4*)&s_w[ci][tap][c4 * 4];
                acc[c4*4+0] = fmaf(iv, wv.x, acc[c4*4+0]);
                acc[c4*4+1] = fmaf(iv, wv.y, acc[c4*4+1]);
                acc[c4*4+2] = fmaf(iv, wv.z, acc[c4*4+2]);
                acc[c4*4+3] = fmaf(iv, wv.w, acc[c4*4+3]);
            }
        }
    const float av = alpha[0];
    const size_t px = (size_t)((y0 + ty) * 512 + x1 + tx);
    u16* oh = outh + px * 32;
    u16* ol = outl + px * 32;
    #pragma unroll
    for (int g = 0; g < 4; ++g) {
        short8 hv, lv;
        #pragma unroll
        for (int k = 0; k < 8; ++k) {
            float t = acc[g * 8 + k] + s_b[g * 8 + k];
            t = t > 0.f ? t : av * t;
            u16 hh = f2bf(t);
            hv[k] = (short)hh;
            lv[k] = (short)f2bf(t - bf2f(hh));
        }
        *(short8*)(oh + g * 8) = hv;
        *(short8*)(ol + g * 8) = lv;
    }
}

// ---------------------------------------------------------------------------
__global__ void zero_k(float* p, int n)
{
    int i = blockIdx.x * 256 + threadIdx.x;
    if (i < n) p[i] = 0.f;
}

__global__ void ca_kernel(const float* __restrict__ g,
                          const float* __restrict__ c11, const float* __restrict__ c12,
                          const float* __restrict__ c21, const float* __restrict__ c22,
                          const float* __restrict__ c31, const float* __restrict__ c32,
                          float* __restrict__ sOut)
{
    int t = threadIdx.x;
    if (t >= 24) return;
    int head = t / 8, b = t % 8;
    const float* c1 = head == 0 ? c11 : (head == 1 ? c21 : c31);
    const float* c2 = head == 0 ? c12 : (head == 1 ? c22 : c32);
    float m[4], v[4];
    #pragma unroll
    for (int i = 0; i < 4; ++i) m[i] = g[head * 32 + b * 4 + i] * (1.0f / 262144.0f);
    #pragma unroll
    for (int j = 0; j < 4; ++j) {
        float xv = c1[j*4+0]*m[0] + c1[j*4+1]*m[1] + c1[j*4+2]*m[2] + c1[j*4+3]*m[3];
        v[j] = fmaxf(xv, 0.f);
    }
    #pragma unroll
    for (int j = 0; j < 4; ++j) {
        float xv = c2[j*4+0]*v[0] + c2[j*4+1]*v[1] + c2[j*4+2]*v[2] + c2[j*4+3]*v[3];
        sOut[head * 32 + b * 4 + j] = 1.f / (1.f + __expf(-xv));
    }
}

// ---------------------------------------------------------------------------
// Integral image (SAT): 513x513 per (b,c) plane.
// ---------------------------------------------------------------------------
__global__ __launch_bounds__(256)
void sat_row(const float* __restrict__ src, float* __restrict__ S)
{
    const int y  = blockIdx.x;
    const int bc = blockIdx.y;
    float* Sp = S + (size_t)bc * 263169;
    const int tid = threadIdx.x;
    if (y == 0) {
        for (int i = tid; i < 513; i += 256) Sp[i] = 0.f;
        return;
    }
    const float2* row2 = (const float2*)(src + (size_t)bc * HWSZ + (size_t)(y - 1) * 512);
    float2 ab = row2[tid];
    float ps = ab.x + ab.y;
    float v = ps;
    const int lane = tid & 63;
    #pragma unroll
    for (int off = 1; off < 64; off <<= 1) {
        float u = __shfl_up(v, off);
        if (lane >= off) v += u;
    }
    __shared__ float wsum[4];
    const int wv = tid >> 6;
    if (lane == 63) wsum[wv] = v;
    __syncthreads();
    float woff = 0.f;
    #pragma unroll
    for (int k = 0; k < 4; ++k) if (k < wv) woff += wsum[k];
    float excl = woff + v - ps;
    float* o = Sp + (size_t)y * 513;
    if (tid == 0) o[0] = 0.f;
    o[1 + 2 * tid] = excl + ab.x;
    o[2 + 2 * tid] = excl + ab.x + ab.y;
}

__global__ __launch_bounds__(256)
void sat_col(float* __restrict__ S)
{
    const int bc = blockIdx.x;
    const int c  = 1 + blockIdx.y * 256 + threadIdx.x;   // 1..512
    float* P = S + (size_t)bc * 263169 + c;
    float run = 0.f;
    for (int r0 = 1; r0 <= 512; r0 += 16) {
        float v[16];
        #pragma unroll
        for (int i = 0; i < 16; ++i) v[i] = P[(size_t)(r0 + i) * 513];
        #pragma unroll
        for (int i = 0; i < 16; ++i) { run += v[i]; v[i] = run; }
        #pragma unroll
        for (int i = 0; i < 16; ++i) P[(size_t)(r0 + i) * 513] = v[i];
    }
}

__device__ __forceinline__ float boxsum(const float* __restrict__ S, int y, int x, int p)
{
    int y0 = max(y - p, 0), x0 = max(x - p, 0);
    int y1 = min(y + p, 511) + 1, x1 = min(x + p, 511) + 1;
    return S[y1 * 513 + x1] - S[y0 * 513 + x1] - S[y1 * 513 + x0] + S[y0 * 513 + x0];
}

__global__ __launch_bounds__(256)
void fuse_kernel(const float* __restrict__ cur, const float* __restrict__ h,
                 const float* __restrict__ sv, const float* __restrict__ S,
                 float* __restrict__ out, int head)
{
    const int idx = blockIdx.x * 256 + threadIdx.x;
    const int b   = idx >> 18;
    const int rem = idx & 262143;
    const int y   = rem >> 9;
    const int x   = rem & 511;

    const float* sp = sv + head * 32 + b * 4;
    const float* hp = h + (size_t)((head * 8 + b) * 4) * HWSZ + rem;
    float z0 = hp[0]          * sp[0];
    float z1 = hp[HWSZ]       * sp[1];
    float z2 = hp[2 * HWSZ]   * sp[2];
    float z3 = hp[3 * HWSZ]   * sp[3];
    float m  = fmaxf(fmaxf(z0, z1), fmaxf(z2, z3));
    float e0 = __expf(z0 - m), e1 = __expf(z1 - m), e2 = __expf(z2 - m), e3 = __expf(z3 - m);
    float inv = 1.f / (e0 + e1 + e2 + e3);
    float p0 = e0 * inv, p1 = e1 * inv, p2 = e2 * inv, p3 = e3 * inv;

    #pragma unroll
    for (int c = 0; c < 3; ++c) {
        const float* Sp = S + (size_t)(b * 3 + c) * 263169;
        float xv = cur[((size_t)b * 3 + c) * HWSZ + rem];
        float m2 = boxsum(Sp, y, x, 2)  * (1.f / 25.f);
        float m3 = boxsum(Sp, y, x, 7)  * (1.f / 225.f);
        float m4 = boxsum(Sp, y, x, 12) * (1.f / 625.f);
        out[((size_t)b * 3 + c) * HWSZ + rem] = p0 * xv + p1 * m2 + p2 * m3 + p3 * m4;
    }
}

// ---------------------------------------------------------------------------
// Workspace (float units):
//   [0, 8388608)        t1: hi plane (8,388,608 u16) + lo plane  (33.5 MB)
//   [8388608, 25165824) t2: hi plane (16,777,216 u16) + lo plane (67 MB)
//                        (aliased by SAT: 6,316,056 floats)
//   [25165824, +25165824) hbuf NCHW fp32 h logits (100.7 MB)
//   then gbuf/sbuf/packed weights/hb16.  ping aliases t1. ~201.6 MB total.
// ---------------------------------------------------------------------------
extern "C" void kernel_launch(void* const* d_in, const int* in_sizes, int n_in,
                              void* d_out, int out_size, void* d_ws, size_t ws_size,
                              hipStream_t stream)
{
    (void)in_sizes; (void)n_in; (void)out_size; (void)ws_size;
    const float* x    = (const float*)d_in[0];
    const float* bw1  = (const float*)d_in[1];
    const float* bb1  = (const float*)d_in[2];
    const float* a1   = (const float*)d_in[3];
    const float* bw2  = (const float*)d_in[4];
    const float* bb2  = (const float*)d_in[5];
    const float* a2   = (const float*)d_in[6];
    const float* bw3  = (const float*)d_in[7];
    const float* bb3  = (const float*)d_in[8];
    const float* a3   = (const float*)d_in[9];
    const float* h1w  = (const float*)d_in[10];
    const float* h1b  = (const float*)d_in[11];
    const float* h1c1 = (const float*)d_in[12];
    const float* h1c2 = (const float*)d_in[13];
    const float* h2w  = (const float*)d_in[14];
    const float* h2b  = (const float*)d_in[15];
    const float* h2c1 = (const float*)d_in[16];
    const float* h2c2 = (const float*)d_in[17];
    const float* h3w  = (const float*)d_in[18];
    const float* h3b  = (const float*)d_in[19];
    const float* h3c1 = (const float*)d_in[20];
    const float* h3c2 = (const float*)d_in[21];

    float* ws   = (float*)d_ws;
    u16* t1h = (u16*)ws;
    u16* t1l = t1h + 8388608;
    u16* t2h = (u16*)(ws + 8388608);
    u16* t2l = t2h + 16777216;
    float* hbuf = ws + 25165824;
    float* gbuf = hbuf + 25165824;
    float* sbuf = gbuf + 96;
    u16* wb  = (u16*)(sbuf + 96);
    u16* w2h = wb;
    u16* w2l = wb + 18432;
    u16* w3h = wb + 36864;
    u16* w3l = wb + 55296;
    u16* whh = wb + 73728;
    u16* whl = wb + 78336;
    float* hb16 = (float*)(wb + 82944);
    float* SAT  = ws + 8388608;     // alias t2
    float* ping = ws;               // alias t1

    dim3 blk(256);
    dim3 cg(8, 128);

    prep_weights<<<dim3(163), blk, 0, stream>>>(bw2, bw3, h1w, h2w, h3w,
                                                h1b, h2b, h3b,
                                                w2h, w2l, w3h, w3l, whh, whl, hb16);
    zero_k<<<dim3(1), dim3(128), 0, stream>>>(gbuf, 96);

    // per-batch body: x[b] -> t1 -> t2 -> t1 -> heads
    for (int b = 0; b < 8; ++b) {
        conv1_split<<<cg, blk, 0, stream>>>(x + (size_t)b * 3 * HWSZ,
                                            bw1, bb1, a1, t1h, t1l);
        conv_mfma<32, 64><<<cg, blk, 0, stream>>>(t1h, t1l, w2h, w2l, bb2, a2, t2h, t2l);
        conv_mfma<64, 32><<<cg, blk, 0, stream>>>(t2h, t2l, w3h, w3l, bb3, a3, t1h, t1l);
        head_mfma<<<cg, blk, 0, stream>>>(t1h, t1l, whh, whl, hb16, hbuf, gbuf, b);
    }

    ca_kernel<<<dim3(1), dim3(64), 0, stream>>>(gbuf, h1c1, h1c2, h2c1, h2c2,
                                                h3c1, h3c2, sbuf);

    // fuse chain: x -> ping -> ping(in place) -> d_out
    const float* cur = x;
    for (int i = 0; i < 3; ++i) {
        sat_row<<<dim3(513, 24), blk, 0, stream>>>(cur, SAT);
        sat_col<<<dim3(24, 2), blk, 0, stream>>>(SAT);
        float* nxt = (i == 2) ? (float*)d_out : ping;
        fuse_kernel<<<dim3(8192), blk, 0, stream>>>(cur, hbuf, sbuf, SAT, nxt, i);
        cur = nxt;
    }
}

// Round 7
// 1702.569 us; speedup vs baseline: 1.1903x; 1.1903x over previous
//
#include <hip/hip_runtime.h>
#include <hip/hip_fp16.h>
#include <math.h>

#define HWSZ (512*512)
#define PW 516              // padded plane width  (cols -1..514 -> 0..515)
#define PH 514              // padded plane height (rows -1..512 -> 0..513)

typedef unsigned int u32;
typedef unsigned short u16;
typedef __attribute__((ext_vector_type(8))) short short8;
typedef __attribute__((ext_vector_type(4))) float f32x4;

__device__ __forceinline__ u16 f2bf(float f) {
    unsigned u = __float_as_uint(f);
    unsigned r = (u + 0x7FFFu + ((u >> 16) & 1u)) >> 16;
    return (u16)r;
}
__device__ __forceinline__ float bf2f(u16 h) {
    return __uint_as_float((unsigned)h << 16);
}

// ---------------------------------------------------------------------------
// Weight prep: fp32 OIHW -> [tap][co][ci] bf16 hi/lo (Markidis split).
// ---------------------------------------------------------------------------
__global__ void prep_weights(const float* __restrict__ w2, const float* __restrict__ w3,
                             const float* __restrict__ hw1, const float* __restrict__ hw2,
                             const float* __restrict__ hw3,
                             const float* __restrict__ hb1, const float* __restrict__ hb2,
                             const float* __restrict__ hb3,
                             u16* __restrict__ w2h, u16* __restrict__ w2l,
                             u16* __restrict__ w3h, u16* __restrict__ w3l,
                             u16* __restrict__ whh, u16* __restrict__ whl,
                             float* __restrict__ hb16)
{
    int i = blockIdx.x * 256 + threadIdx.x;
    if (i < 18432) {
        int tap = i / 2048, r = i % 2048, co = r / 32, ci = r % 32;
        float v = w2[((co * 32 + ci) * 9) + tap];
        u16 h = f2bf(v);
        w2h[i] = h; w2l[i] = f2bf(v - bf2f(h));
    } else if (i < 36864) {
        int e = i - 18432;
        int tap = e / 2048, r = e % 2048, co = r / 64, ci = r % 64;
        float v = w3[((co * 64 + ci) * 9) + tap];
        u16 h = f2bf(v);
        w3h[e] = h; w3l[e] = f2bf(v - bf2f(h));
    } else if (i < 41472) {
        int e = i - 36864;
        int tap = e / 512, r = e % 512, co16 = r / 32, ci = r % 32;
        float v = 0.f;
        if (co16 < 12) {
            int hd = co16 >> 2, cl = co16 & 3;
            const float* wp = hd == 0 ? hw1 : (hd == 1 ? hw2 : hw3);
            v = wp[((cl * 32 + ci) * 9) + tap];
        }
        u16 h = f2bf(v);
        whh[e] = h; whl[e] = f2bf(v - bf2f(h));
    } else if (i < 41488) {
        int j = i - 41472;
        float v = 0.f;
        if (j < 12) {
            const float* bp = (j >> 2) == 0 ? hb1 : ((j >> 2) == 1 ? hb2 : hb3);
            v = bp[j & 3];
        }
        hb16[j] = v;
    }
}

// ---------------------------------------------------------------------------
// Zero the pad border of the 4 split planes (rows 0/513 full, cols 0/513).
// ---------------------------------------------------------------------------
__global__ void zero_pads(u16* __restrict__ t1h, u16* __restrict__ t1l,
                          u16* __restrict__ t2h, u16* __restrict__ t2l)
{
    const int pl = blockIdx.y;
    u16* base = pl == 0 ? t1h : (pl == 1 ? t1l : (pl == 2 ? t2h : t2l));
    const int C = pl < 2 ? 32 : 64;
    int i = blockIdx.x * 256 + threadIdx.x;
    if (i >= 2056) return;
    int row, col;
    if (i < 516)       { row = 0;            col = i; }
    else if (i < 1032) { row = 513;          col = i - 516; }
    else if (i < 1544) { row = i - 1032 + 1; col = 0; }
    else               { row = i - 1544 + 1; col = 513; }
    u16* p = base + ((size_t)row * PW + col) * C;
    const short8 zz = {0,0,0,0,0,0,0,0};
    for (int k = 0; k < C; k += 8) *(short8*)(p + k) = zz;
}

// ---------------------------------------------------------------------------
// 3x3 conv + bias + PReLU; padded split-plane bf16 hi/lo in/out.
// Staging: async global_load_lds (16B/lane) -> LDS [6 rows][68 px][32 ci]/plane.
// Compute: 3-pass compensated bf16 MFMA 16x16x32, pass-major ordering.
// Epilogue: LDS transpose -> coalesced 16B split-plane stores.
// ---------------------------------------------------------------------------
template<int CIN, int COUT>
__global__ __launch_bounds__(256, 3)
void conv_mfma(const u16* __restrict__ inh, const u16* __restrict__ inl,
               const u16* __restrict__ wh, const u16* __restrict__ wl,
               const float* __restrict__ bias, const float* __restrict__ alpha,
               u16* __restrict__ outh, u16* __restrict__ outl)
{
    constexpr int NTW  = COUT / 16;
    constexpr int RSTR = 68 * 32;          // u16 per LDS row (68 slots x 32 ci)
    constexpr int PL   = 6 * RSTR;         // u16 per plane
    __shared__ __align__(16) u16 s_a[2 * PL];   // 52,224 B

    const int tid  = threadIdx.x;
    const int w    = tid >> 6;
    const int lane = tid & 63;
    const int ln   = lane & 15;
    const int quad = lane >> 4;
    const int x1   = blockIdx.x * 64;
    const int y0   = blockIdx.y * 4;

    const int px_off = lane >> 2;          // 0..15
    const int ci_off = (lane & 3) * 8;

    f32x4 acc[4][NTW];
    #pragma unroll
    for (int mt = 0; mt < 4; ++mt)
        #pragma unroll
        for (int nt = 0; nt < NTW; ++nt)
            acc[mt][nt] = (f32x4){0.f, 0.f, 0.f, 0.f};

    #pragma unroll 1
    for (int kk = 0; kk < CIN / 32; ++kk) {
        if (kk) __syncthreads();
        // ---- async staging: 12 row-plane units x (4 full + 1 partial) DMA ----
        for (int u = w; u < 12; u += 4) {
            const int r = u >> 1, p = u & 1;
            const u16* g = (p ? inl : inh)
                         + ((size_t)(y0 + r) * PW + x1) * CIN + kk * 32 + ci_off;
            u16* lb = s_a + p * PL + r * RSTR;
            #pragma unroll
            for (int j = 0; j < 4; ++j)
                __builtin_amdgcn_global_load_lds(
                    (const void*)(g + (size_t)(j * 16 + px_off) * CIN),
                    (void*)(lb + j * 512), 16, 0, 0);
            if (lane < 16)
                __builtin_amdgcn_global_load_lds(
                    (const void*)(g + (size_t)(64 + px_off) * CIN),
                    (void*)(lb + 4 * 512), 16, 0, 0);
        }
        __syncthreads();

        // ---- compute: 9 taps x 3 passes ----
        #pragma unroll
        for (int tap = 0; tap < 9; ++tap) {
            const int dy = tap / 3, dx = tap % 3;
            short8 bh[NTW], bl[NTW];
            #pragma unroll
            for (int nt = 0; nt < NTW; ++nt) {
                const size_t boff = ((size_t)(tap * COUT + nt * 16 + ln)) * CIN + kk * 32 + quad * 8;
                bh[nt] = *(const short8*)(wh + boff);
                bl[nt] = *(const short8*)(wl + boff);
            }
            short8 ah[4], al[4];
            #pragma unroll
            for (int mt = 0; mt < 4; ++mt) {
                const int off = (w + dy) * RSTR + (mt * 16 + ln + dx) * 32 + quad * 8;
                ah[mt] = *(const short8*)(s_a + off);
                al[mt] = *(const short8*)(s_a + PL + off);
            }
            #pragma unroll
            for (int mt = 0; mt < 4; ++mt)
                #pragma unroll
                for (int nt = 0; nt < NTW; ++nt)
                    acc[mt][nt] = __builtin_amdgcn_mfma_f32_16x16x32_bf16(ah[mt], bh[nt], acc[mt][nt], 0, 0, 0);
            #pragma unroll
            for (int mt = 0; mt < 4; ++mt)
                #pragma unroll
                for (int nt = 0; nt < NTW; ++nt)
                    acc[mt][nt] = __builtin_amdgcn_mfma_f32_16x16x32_bf16(al[mt], bh[nt], acc[mt][nt], 0, 0, 0);
            #pragma unroll
            for (int mt = 0; mt < 4; ++mt)
                #pragma unroll
                for (int nt = 0; nt < NTW; ++nt)
                    acc[mt][nt] = __builtin_amdgcn_mfma_f32_16x16x32_bf16(ah[mt], bl[nt], acc[mt][nt], 0, 0, 0);
        }
    }

    // ---- epilogue: transpose via LDS, coalesced split-plane stores ----
    const float av = alpha[0];
    u32* s_t = (u32*)s_a;                   // [256 px][stride 34] u32
    __syncthreads();
    #pragma unroll 1
    for (int pp = 0; pp < COUT / 32; ++pp) {
        if (pp) __syncthreads();
        #pragma unroll
        for (int nn = 0; nn < 2; ++nn) {
            const int nt = pp * 2 + nn;
            const float bs = bias[nt * 16 + ln];
            #pragma unroll
            for (int mt = 0; mt < 4; ++mt)
                #pragma unroll
                for (int reg = 0; reg < 4; ++reg) {
                    float t = acc[mt][nt][reg] + bs;
                    t = t > 0.f ? t : av * t;
                    u16 h = f2bf(t);
                    u16 l = f2bf(t - bf2f(h));
                    const int tp = w * 64 + mt * 16 + quad * 4 + reg;
                    s_t[tp * 34 + nn * 16 + ln] = (u32)h | ((u32)l << 16);
                }
        }
        __syncthreads();
        {
            const int r = tid >> 6, c = tid & 63;
            const size_t gb = ((size_t)(y0 + r + 1) * PW + (x1 + c + 1)) * COUT + pp * 32;
            const u32* rowp = s_t + tid * 34;
            #pragma unroll
            for (int gq = 0; gq < 4; ++gq) {
                uint2 a0 = *(const uint2*)(rowp + gq * 8);
                uint2 a1 = *(const uint2*)(rowp + gq * 8 + 2);
                uint2 a2 = *(const uint2*)(rowp + gq * 8 + 4);
                uint2 a3 = *(const uint2*)(rowp + gq * 8 + 6);
                uint4 hq, lq;
                hq.x = (a0.x & 0xffffu) | (a0.y << 16);
                hq.y = (a1.x & 0xffffu) | (a1.y << 16);
                hq.z = (a2.x & 0xffffu) | (a2.y << 16);
                hq.w = (a3.x & 0xffffu) | (a3.y << 16);
                lq.x = (a0.x >> 16) | (a0.y & 0xffff0000u);
                lq.y = (a1.x >> 16) | (a1.y & 0xffff0000u);
                lq.z = (a2.x >> 16) | (a2.y & 0xffff0000u);
                lq.w = (a3.x >> 16) | (a3.y & 0xffff0000u);
                *(uint4*)(outh + gb + gq * 8) = hq;
                *(uint4*)(outl + gb + gq * 8) = lq;
            }
        }
    }
}

// ---------------------------------------------------------------------------
// Head conv 32 -> 16 co (12 valid): async-staged MFMA + GAP atomics.
// Writes h as fp16 [head][b][px][4] (8B/px vector stores via LDS transpose).
// ---------------------------------------------------------------------------
__global__ __launch_bounds__(256, 3)
void head_mfma(const u16* __restrict__ inh, const u16* __restrict__ inl,
               const u16* __restrict__ wh, const u16* __restrict__ wl,
               const float* __restrict__ hb,
               __half* __restrict__ hbuf, float* __restrict__ g2, int b)
{
    constexpr int RSTR = 68 * 32;
    constexpr int PL   = 6 * RSTR;
    __shared__ __align__(16) u16 s_a[2 * PL];
    __shared__ float s_red[4][16];

    const int tid  = threadIdx.x;
    const int w    = tid >> 6;
    const int lane = tid & 63;
    const int ln   = lane & 15;
    const int quad = lane >> 4;
    const int x1   = blockIdx.x * 64;
    const int y0   = blockIdx.y * 4;
    const int px_off = lane >> 2;
    const int ci_off = (lane & 3) * 8;

    f32x4 acc[4];
    #pragma unroll
    for (int mt = 0; mt < 4; ++mt) acc[mt] = (f32x4){0.f, 0.f, 0.f, 0.f};

    for (int u = w; u < 12; u += 4) {
        const int r = u >> 1, p = u & 1;
        const u16* g = (p ? inl : inh) + ((size_t)(y0 + r) * PW + x1) * 32 + ci_off;
        u16* lb = s_a + p * PL + r * RSTR;
        #pragma unroll
        for (int j = 0; j < 4; ++j)
            __builtin_amdgcn_global_load_lds(
                (const void*)(g + (size_t)(j * 16 + px_off) * 32),
                (void*)(lb + j * 512), 16, 0, 0);
        if (lane < 16)
            __builtin_amdgcn_global_load_lds(
                (const void*)(g + (size_t)(64 + px_off) * 32),
                (void*)(lb + 4 * 512), 16, 0, 0);
    }
    __syncthreads();

    #pragma unroll
    for (int tap = 0; tap < 9; ++tap) {
        const int dy = tap / 3, dx = tap % 3;
        const size_t boff = (size_t)tap * 512 + ln * 32 + quad * 8;
        short8 bh = *(const short8*)(wh + boff);
        short8 bl = *(const short8*)(wl + boff);
        short8 ah[4], al[4];
        #pragma unroll
        for (int mt = 0; mt < 4; ++mt) {
            const int off = (w + dy) * RSTR + (mt * 16 + ln + dx) * 32 + quad * 8;
            ah[mt] = *(const short8*)(s_a + off);
            al[mt] = *(const short8*)(s_a + PL + off);
        }
        #pragma unroll
        for (int mt = 0; mt < 4; ++mt)
            acc[mt] = __builtin_amdgcn_mfma_f32_16x16x32_bf16(ah[mt], bh, acc[mt], 0, 0, 0);
        #pragma unroll
        for (int mt = 0; mt < 4; ++mt)
            acc[mt] = __builtin_amdgcn_mfma_f32_16x16x32_bf16(al[mt], bh, acc[mt], 0, 0, 0);
        #pragma unroll
        for (int mt = 0; mt < 4; ++mt)
            acc[mt] = __builtin_amdgcn_mfma_f32_16x16x32_bf16(ah[mt], bl, acc[mt], 0, 0, 0);
    }

    __syncthreads();                       // done reading s_a; reuse as f32 scratch
    float* s_hf = (float*)s_a;             // [256 px][stride 20] floats
    const float bs = hb[ln];
    float psum = 0.f;
    #pragma unroll
    for (int mt = 0; mt < 4; ++mt) {
        #pragma unroll
        for (int reg = 0; reg < 4; ++reg) {
            float v = acc[mt][reg] + bs;
            const int tp = w * 64 + mt * 16 + quad * 4 + reg;
            if (ln < 12) s_hf[tp * 20 + ln] = v;
            psum += v;                     // co >= 12: zero weights+bias -> 0
        }
    }
    psum += __shfl_down(psum, 16);
    psum += __shfl_down(psum, 32);
    if (lane < 16) s_red[w][lane] = psum;
    __syncthreads();

    {
        const int r = tid >> 6, c = tid & 63;
        const float* src = s_hf + tid * 20;
        float4 v0 = *(const float4*)(src);
        float4 v1 = *(const float4*)(src + 4);
        float4 v2 = *(const float4*)(src + 8);
        const size_t gpx = (size_t)(y0 + r) * 512 + x1 + c;
        float vv[12] = {v0.x, v0.y, v0.z, v0.w, v1.x, v1.y, v1.z, v1.w,
                        v2.x, v2.y, v2.z, v2.w};
        #pragma unroll
        for (int hd = 0; hd < 3; ++hd) {
            ushort4 u;
            u.x = __half_as_ushort(__float2half_rn(vv[hd * 4 + 0]));
            u.y = __half_as_ushort(__float2half_rn(vv[hd * 4 + 1]));
            u.z = __half_as_ushort(__float2half_rn(vv[hd * 4 + 2]));
            u.w = __half_as_ushort(__float2half_rn(vv[hd * 4 + 3]));
            *(ushort4*)((u16*)hbuf + ((size_t)(hd * 8 + b) * HWSZ + gpx) * 4) = u;
        }
    }
    if (tid < 12) {
        float t = s_red[0][tid] + s_red[1][tid] + s_red[2][tid] + s_red[3][tid];
        atomicAdd(&g2[(tid >> 2) * 32 + b * 4 + (tid & 3)], t);
    }
}

// ---------------------------------------------------------------------------
// conv1: 3 -> 32, fp32 direct, thread-per-pixel, writes padded split planes.
// ---------------------------------------------------------------------------
__global__ __launch_bounds__(256)
void conv1_pad(const float* __restrict__ x, const float* __restrict__ wgt,
               const float* __restrict__ bias, const float* __restrict__ alpha,
               u16* __restrict__ outh, u16* __restrict__ outl)
{
    __shared__ float s_in[3][6][72];
    __shared__ float s_w[3][9][32];
    __shared__ float s_b[32];
    const int tid = threadIdx.x;
    const int x1 = blockIdx.x * 64, y0 = blockIdx.y * 4;

    for (int i = tid; i < 3 * 6 * 66; i += 256) {
        int ci = i / 396, rm = i % 396;
        int r = rm / 66, cc = rm % 66;
        int gy = y0 - 1 + r, gx = x1 - 1 + cc;
        float v = 0.f;
        if ((unsigned)gy < 512u && (unsigned)gx < 512u)
            v = x[(size_t)ci * HWSZ + gy * 512 + gx];
        s_in[ci][r][cc] = v;
    }
    for (int i = tid; i < 864; i += 256) {
        int co = i & 31, rm = i >> 5;
        int ci = rm / 9, tap = rm % 9;
        s_w[ci][tap][co] = wgt[(co * 3 + ci) * 9 + tap];
    }
    if (tid < 32) s_b[tid] = bias[tid];
    __syncthreads();

    const int ty = tid >> 6, tx = tid & 63;
    float acc[32];
    #pragma unroll
    for (int i = 0; i < 32; ++i) acc[i] = 0.f;
    #pragma unroll
    for (int ci = 0; ci < 3; ++ci)
        #pragma unroll
        for (int tap = 0; tap < 9; ++tap) {
            const int dy = tap / 3, dx = tap % 3;
            float iv = s_in[ci][ty + dy][tx + dx];
            #pragma unroll
            for (int c4 = 0; c4 < 8; ++c4) {
                float4 wv = *(const float4*)&s_w[ci][tap][c4 * 4];
                acc[c4*4+0] = fmaf(iv, wv.x, acc[c4*4+0]);
                acc[c4*4+1] = fmaf(iv, wv.y, acc[c4*4+1]);
                acc[c4*4+2] = fmaf(iv, wv.z, acc[c4*4+2]);
                acc[c4*4+3] = fmaf(iv, wv.w, acc[c4*4+3]);
            }
        }
    const float av = alpha[0];
    const size_t pb = ((size_t)(y0 + ty + 1) * PW + (x1 + tx + 1)) * 32;
    #pragma unroll
    for (int g = 0; g < 4; ++g) {
        short8 hv, lv;
        #pragma unroll
        for (int k = 0; k < 8; ++k) {
            float t = acc[g * 8 + k] + s_b[g * 8 + k];
            t = t > 0.f ? t : av * t;
            u16 hh = f2bf(t);
            hv[k] = (short)hh;
            lv[k] = (short)f2bf(t - bf2f(hh));
        }
        *(short8*)(outh + pb + g * 8) = hv;
        *(short8*)(outl + pb + g * 8) = lv;
    }
}

// ---------------------------------------------------------------------------
__global__ void zero_k(float* p, int n)
{
    int i = blockIdx.x * 256 + threadIdx.x;
    if (i < n) p[i] = 0.f;
}

__global__ void ca_kernel(const float* __restrict__ g,
                          const float* __restrict__ c11, const float* __restrict__ c12,
                          const float* __restrict__ c21, const float* __restrict__ c22,
                          const float* __restrict__ c31, const float* __restrict__ c32,
                          float* __restrict__ sOut)
{
    int t = threadIdx.x;
    if (t >= 24) return;
    int head = t / 8, b = t % 8;
    const float* c1 = head == 0 ? c11 : (head == 1 ? c21 : c31);
    const float* c2 = head == 0 ? c12 : (head == 1 ? c22 : c32);
    float m[4], v[4];
    #pragma unroll
    for (int i = 0; i < 4; ++i) m[i] = g[head * 32 + b * 4 + i] * (1.0f / 262144.0f);
    #pragma unroll
    for (int j = 0; j < 4; ++j) {
        float xv = c1[j*4+0]*m[0] + c1[j*4+1]*m[1] + c1[j*4+2]*m[2] + c1[j*4+3]*m[3];
        v[j] = fmaxf(xv, 0.f);
    }
    #pragma unroll
    for (int j = 0; j < 4; ++j) {
        float xv = c2[j*4+0]*v[0] + c2[j*4+1]*v[1] + c2[j*4+2]*v[2] + c2[j*4+3]*v[3];
        sOut[head * 32 + b * 4 + j] = 1.f / (1.f + __expf(-xv));
    }
}

// ---------------------------------------------------------------------------
// Integral image (SAT): 513x513 per (b,c) plane.
// ---------------------------------------------------------------------------
__global__ __launch_bounds__(256)
void sat_row(const float* __restrict__ src, float* __restrict__ S)
{
    const int y  = blockIdx.x;
    const int bc = blockIdx.y;
    float* Sp = S + (size_t)bc * 263169;
    const int tid = threadIdx.x;
    if (y == 0) {
        for (int i = tid; i < 513; i += 256) Sp[i] = 0.f;
        return;
    }
    const float2* row2 = (const float2*)(src + (size_t)bc * HWSZ + (size_t)(y - 1) * 512);
    float2 ab = row2[tid];
    float ps = ab.x + ab.y;
    float v = ps;
    const int lane = tid & 63;
    #pragma unroll
    for (int off = 1; off < 64; off <<= 1) {
        float u = __shfl_up(v, off);
        if (lane >= off) v += u;
    }
    __shared__ float wsum[4];
    const int wv = tid >> 6;
    if (lane == 63) wsum[wv] = v;
    __syncthreads();
    float woff = 0.f;
    #pragma unroll
    for (int k = 0; k < 4; ++k) if (k < wv) woff += wsum[k];
    float excl = woff + v - ps;
    float* o = Sp + (size_t)y * 513;
    if (tid == 0) o[0] = 0.f;
    o[1 + 2 * tid] = excl + ab.x;
    o[2 + 2 * tid] = excl + ab.x + ab.y;
}

__global__ __launch_bounds__(256)
void sat_col(float* __restrict__ S)
{
    const int bc = blockIdx.x;
    const int c  = 1 + blockIdx.y * 256 + threadIdx.x;
    float* P = S + (size_t)bc * 263169 + c;
    float run = 0.f;
    for (int r0 = 1; r0 <= 512; r0 += 16) {
        float v[16];
        #pragma unroll
        for (int i = 0; i < 16; ++i) v[i] = P[(size_t)(r0 + i) * 513];
        #pragma unroll
        for (int i = 0; i < 16; ++i) { run += v[i]; v[i] = run; }
        #pragma unroll
        for (int i = 0; i < 16; ++i) P[(size_t)(r0 + i) * 513] = v[i];
    }
}

__device__ __forceinline__ float boxsum(const float* __restrict__ S, int y, int x, int p)
{
    int y0 = max(y - p, 0), x0 = max(x - p, 0);
    int y1 = min(y + p, 511) + 1, x1 = min(x + p, 511) + 1;
    return S[y1 * 513 + x1] - S[y0 * 513 + x1] - S[y1 * 513 + x0] + S[y0 * 513 + x0];
}

__global__ __launch_bounds__(256)
void fuse_kernel(const float* __restrict__ cur, const __half* __restrict__ h,
                 const float* __restrict__ sv, const float* __restrict__ S,
                 float* __restrict__ out, int head)
{
    const int idx = blockIdx.x * 256 + threadIdx.x;
    const int b   = idx >> 18;
    const int rem = idx & 262143;
    const int y   = rem >> 9;
    const int x   = rem & 511;

    const float* sp = sv + head * 32 + b * 4;
    const __half* hp = h + ((size_t)(head * 8 + b) * HWSZ + rem) * 4;
    float z0 = __half2float(hp[0]) * sp[0];
    float z1 = __half2float(hp[1]) * sp[1];
    float z2 = __half2float(hp[2]) * sp[2];
    float z3 = __half2float(hp[3]) * sp[3];
    float m  = fmaxf(fmaxf(z0, z1), fmaxf(z2, z3));
    float e0 = __expf(z0 - m), e1 = __expf(z1 - m), e2 = __expf(z2 - m), e3 = __expf(z3 - m);
    float inv = 1.f / (e0 + e1 + e2 + e3);
    float p0 = e0 * inv, p1 = e1 * inv, p2 = e2 * inv, p3 = e3 * inv;

    #pragma unroll
    for (int c = 0; c < 3; ++c) {
        const float* Sp = S + (size_t)(b * 3 + c) * 263169;
        float xv = cur[((size_t)b * 3 + c) * HWSZ + rem];
        float m2 = boxsum(Sp, y, x, 2)  * (1.f / 25.f);
        float m3 = boxsum(Sp, y, x, 7)  * (1.f / 225.f);
        float m4 = boxsum(Sp, y, x, 12) * (1.f / 625.f);
        out[((size_t)b * 3 + c) * HWSZ + rem] = p0 * xv + p1 * m2 + p2 * m3 + p3 * m4;
    }
}

// ---------------------------------------------------------------------------
// Workspace (u16 units):
//   t1h/t1l: 8,487,168 each   (514x516x32 padded bf16 planes)
//   t2h/t2l: 16,974,336 each  (514x516x64)
//   hbuf: 25,165,824 halfs    ([3 heads][8 b][HW][4 ch] fp16)
//   gbuf/sbuf/weights: small.  Total ~152.5 MB. SAT aliases t2, ping aliases t1.
// ---------------------------------------------------------------------------
extern "C" void kernel_launch(void* const* d_in, const int* in_sizes, int n_in,
                              void* d_out, int out_size, void* d_ws, size_t ws_size,
                              hipStream_t stream)
{
    (void)in_sizes; (void)n_in; (void)out_size; (void)ws_size;
    const float* x    = (const float*)d_in[0];
    const float* bw1  = (const float*)d_in[1];
    const float* bb1  = (const float*)d_in[2];
    const float* a1   = (const float*)d_in[3];
    const float* bw2  = (const float*)d_in[4];
    const float* bb2  = (const float*)d_in[5];
    const float* a2   = (const float*)d_in[6];
    const float* bw3  = (const float*)d_in[7];
    const float* bb3  = (const float*)d_in[8];
    const float* a3   = (const float*)d_in[9];
    const float* h1w  = (const float*)d_in[10];
    const float* h1b  = (const float*)d_in[11];
    const float* h1c1 = (const float*)d_in[12];
    const float* h1c2 = (const float*)d_in[13];
    const float* h2w  = (const float*)d_in[14];
    const float* h2b  = (const float*)d_in[15];
    const float* h2c1 = (const float*)d_in[16];
    const float* h2c2 = (const float*)d_in[17];
    const float* h3w  = (const float*)d_in[18];
    const float* h3b  = (const float*)d_in[19];
    const float* h3c1 = (const float*)d_in[20];
    const float* h3c2 = (const float*)d_in[21];

    u16* b16 = (u16*)d_ws;
    const size_t T1P = (size_t)PH * PW * 32;   // 8,487,168
    const size_t T2P = (size_t)PH * PW * 64;   // 16,974,336
    u16* t1h = b16;
    u16* t1l = t1h + T1P;
    u16* t2h = t1l + T1P;
    u16* t2l = t2h + T2P;
    __half* hbuf = (__half*)(t2l + T2P);
    float* gbuf = (float*)((u16*)hbuf + 25165824);
    float* sbuf = gbuf + 96;
    u16* wb  = (u16*)(sbuf + 96);
    u16* w2h = wb;
    u16* w2l = wb + 18432;
    u16* w3h = wb + 36864;
    u16* w3l = wb + 55296;
    u16* whh = wb + 73728;
    u16* whl = wb + 78336;
    float* hb16 = (float*)(wb + 82944);
    float* SAT  = (float*)t2h;          // t2 dead after batch loop
    float* ping = (float*)t1h;          // t1 dead after batch loop

    dim3 blk(256);
    dim3 cg(8, 128);

    prep_weights<<<dim3(163), blk, 0, stream>>>(bw2, bw3, h1w, h2w, h3w,
                                                h1b, h2b, h3b,
                                                w2h, w2l, w3h, w3l, whh, whl, hb16);
    zero_pads<<<dim3(9, 4), blk, 0, stream>>>(t1h, t1l, t2h, t2l);
    zero_k<<<dim3(1), dim3(128), 0, stream>>>(gbuf, 96);

    // per-batch body: x[b] -> t1 -> t2 -> t1 -> heads
    for (int b = 0; b < 8; ++b) {
        conv1_pad<<<cg, blk, 0, stream>>>(x + (size_t)b * 3 * HWSZ,
                                          bw1, bb1, a1, t1h, t1l);
        conv_mfma<32, 64><<<cg, blk, 0, stream>>>(t1h, t1l, w2h, w2l, bb2, a2, t2h, t2l);
        conv_mfma<64, 32><<<cg, blk, 0, stream>>>(t2h, t2l, w3h, w3l, bb3, a3, t1h, t1l);
        head_mfma<<<cg, blk, 0, stream>>>(t1h, t1l, whh, whl, hb16, hbuf, gbuf, b);
    }

    ca_kernel<<<dim3(1), dim3(64), 0, stream>>>(gbuf, h1c1, h1c2, h2c1, h2c2,
                                                h3c1, h3c2, sbuf);

    // fuse chain: x -> ping -> ping(in place) -> d_out
    const float* cur = x;
    for (int i = 0; i < 3; ++i) {
        sat_row<<<dim3(513, 24), blk, 0, stream>>>(cur, SAT);
        sat_col<<<dim3(24, 2), blk, 0, stream>>>(SAT);
        float* nxt = (i == 2) ? (float*)d_out : ping;
        fuse_kernel<<<dim3(8192), blk, 0, stream>>>(cur, hbuf, sbuf, SAT, nxt, i);
        cur = nxt;
    }
}

// Round 8
// 1623.079 us; speedup vs baseline: 1.2486x; 1.0490x over previous
//
#include <hip/hip_runtime.h>
#include <hip/hip_fp16.h>
#include <math.h>

#define HWSZ (512*512)
#define PW 516              // padded plane width  (cols -1..514 -> 0..515)
#define PH 514              // padded plane height (rows -1..512 -> 0..513)

typedef unsigned int u32;
typedef unsigned short u16;
typedef __attribute__((ext_vector_type(8))) short short8;
typedef __attribute__((ext_vector_type(4))) float f32x4;

__device__ __forceinline__ u16 f2bf(float f) {
    unsigned u = __float_as_uint(f);
    unsigned r = (u + 0x7FFFu + ((u >> 16) & 1u)) >> 16;
    return (u16)r;
}
__device__ __forceinline__ float bf2f(u16 h) {
    return __uint_as_float((unsigned)h << 16);
}

// ---------------------------------------------------------------------------
// Weight prep: fp32 OIHW -> [tap][co][ci] bf16 hi/lo (Markidis split).
// ---------------------------------------------------------------------------
__global__ void prep_weights(const float* __restrict__ w2, const float* __restrict__ w3,
                             const float* __restrict__ hw1, const float* __restrict__ hw2,
                             const float* __restrict__ hw3,
                             const float* __restrict__ hb1, const float* __restrict__ hb2,
                             const float* __restrict__ hb3,
                             u16* __restrict__ w2h, u16* __restrict__ w2l,
                             u16* __restrict__ w3h, u16* __restrict__ w3l,
                             u16* __restrict__ whh, u16* __restrict__ whl,
                             float* __restrict__ hb16)
{
    int i = blockIdx.x * 256 + threadIdx.x;
    if (i < 18432) {
        int tap = i / 2048, r = i % 2048, co = r / 32, ci = r % 32;
        float v = w2[((co * 32 + ci) * 9) + tap];
        u16 h = f2bf(v);
        w2h[i] = h; w2l[i] = f2bf(v - bf2f(h));
    } else if (i < 36864) {
        int e = i - 18432;
        int tap = e / 2048, r = e % 2048, co = r / 64, ci = r % 64;
        float v = w3[((co * 64 + ci) * 9) + tap];
        u16 h = f2bf(v);
        w3h[e] = h; w3l[e] = f2bf(v - bf2f(h));
    } else if (i < 41472) {
        int e = i - 36864;
        int tap = e / 512, r = e % 512, co16 = r / 32, ci = r % 32;
        float v = 0.f;
        if (co16 < 12) {
            int hd = co16 >> 2, cl = co16 & 3;
            const float* wp = hd == 0 ? hw1 : (hd == 1 ? hw2 : hw3);
            v = wp[((cl * 32 + ci) * 9) + tap];
        }
        u16 h = f2bf(v);
        whh[e] = h; whl[e] = f2bf(v - bf2f(h));
    } else if (i < 41488) {
        int j = i - 41472;
        float v = 0.f;
        if (j < 12) {
            const float* bp = (j >> 2) == 0 ? hb1 : ((j >> 2) == 1 ? hb2 : hb3);
            v = bp[j & 3];
        }
        hb16[j] = v;
    }
}

// ---------------------------------------------------------------------------
// Zero the pad border of the 4 split planes (rows 0/513 full, cols 0/513).
// ---------------------------------------------------------------------------
__global__ void zero_pads(u16* __restrict__ t1h, u16* __restrict__ t1l,
                          u16* __restrict__ t2h, u16* __restrict__ t2l)
{
    const int pl = blockIdx.y;
    u16* base = pl == 0 ? t1h : (pl == 1 ? t1l : (pl == 2 ? t2h : t2l));
    const int C = pl < 2 ? 32 : 64;
    int i = blockIdx.x * 256 + threadIdx.x;
    if (i >= 2056) return;
    int row, col;
    if (i < 516)       { row = 0;            col = i; }
    else if (i < 1032) { row = 513;          col = i - 516; }
    else if (i < 1544) { row = i - 1032 + 1; col = 0; }
    else               { row = i - 1544 + 1; col = 513; }
    u16* p = base + ((size_t)row * PW + col) * C;
    const short8 zz = {0,0,0,0,0,0,0,0};
    for (int k = 0; k < C; k += 8) *(short8*)(p + k) = zz;
}

// ---------------------------------------------------------------------------
// 3x3 conv + bias + PReLU; padded split-plane bf16 hi/lo in/out.
// Staging: async global_load_lds (16B/lane) -> LDS [6 rows][68 px][32 ci]/plane.
// Compute: 3-pass compensated bf16 MFMA 16x16x32, pass-major ordering.
// Epilogue: LDS transpose -> FULL-SECTOR coalesced stores (4 lanes x 16B cover
// each 64-B half-pixel chunk completely -> no partial-sector write-amp).
// ---------------------------------------------------------------------------
template<int CIN, int COUT>
__global__ __launch_bounds__(256, 3)
void conv_mfma(const u16* __restrict__ inh, const u16* __restrict__ inl,
               const u16* __restrict__ wh, const u16* __restrict__ wl,
               const float* __restrict__ bias, const float* __restrict__ alpha,
               u16* __restrict__ outh, u16* __restrict__ outl)
{
    constexpr int NTW  = COUT / 16;
    constexpr int RSTR = 68 * 32;          // u16 per LDS row (68 slots x 32 ci)
    constexpr int PL   = 6 * RSTR;         // u16 per plane
    __shared__ __align__(16) u16 s_a[2 * PL];   // 52,224 B

    const int tid  = threadIdx.x;
    const int w    = tid >> 6;
    const int lane = tid & 63;
    const int ln   = lane & 15;
    const int quad = lane >> 4;
    const int x1   = blockIdx.x * 64;
    const int y0   = blockIdx.y * 4;

    const int px_off = lane >> 2;          // 0..15
    const int ci_off = (lane & 3) * 8;

    f32x4 acc[4][NTW];
    #pragma unroll
    for (int mt = 0; mt < 4; ++mt)
        #pragma unroll
        for (int nt = 0; nt < NTW; ++nt)
            acc[mt][nt] = (f32x4){0.f, 0.f, 0.f, 0.f};

    #pragma unroll 1
    for (int kk = 0; kk < CIN / 32; ++kk) {
        if (kk) __syncthreads();
        // ---- async staging: 12 row-plane units x (4 full + 1 partial) DMA ----
        for (int u = w; u < 12; u += 4) {
            const int r = u >> 1, p = u & 1;
            const u16* g = (p ? inl : inh)
                         + ((size_t)(y0 + r) * PW + x1) * CIN + kk * 32 + ci_off;
            u16* lb = s_a + p * PL + r * RSTR;
            #pragma unroll
            for (int j = 0; j < 4; ++j)
                __builtin_amdgcn_global_load_lds(
                    (const void*)(g + (size_t)(j * 16 + px_off) * CIN),
                    (void*)(lb + j * 512), 16, 0, 0);
            if (lane < 16)
                __builtin_amdgcn_global_load_lds(
                    (const void*)(g + (size_t)(64 + px_off) * CIN),
                    (void*)(lb + 4 * 512), 16, 0, 0);
        }
        __syncthreads();

        // ---- compute: 9 taps x 3 passes ----
        #pragma unroll
        for (int tap = 0; tap < 9; ++tap) {
            const int dy = tap / 3, dx = tap % 3;
            short8 bh[NTW], bl[NTW];
            #pragma unroll
            for (int nt = 0; nt < NTW; ++nt) {
                const size_t boff = ((size_t)(tap * COUT + nt * 16 + ln)) * CIN + kk * 32 + quad * 8;
                bh[nt] = *(const short8*)(wh + boff);
                bl[nt] = *(const short8*)(wl + boff);
            }
            short8 ah[4], al[4];
            #pragma unroll
            for (int mt = 0; mt < 4; ++mt) {
                const int off = (w + dy) * RSTR + (mt * 16 + ln + dx) * 32 + quad * 8;
                ah[mt] = *(const short8*)(s_a + off);
                al[mt] = *(const short8*)(s_a + PL + off);
            }
            #pragma unroll
            for (int mt = 0; mt < 4; ++mt)
                #pragma unroll
                for (int nt = 0; nt < NTW; ++nt)
                    acc[mt][nt] = __builtin_amdgcn_mfma_f32_16x16x32_bf16(ah[mt], bh[nt], acc[mt][nt], 0, 0, 0);
            #pragma unroll
            for (int mt = 0; mt < 4; ++mt)
                #pragma unroll
                for (int nt = 0; nt < NTW; ++nt)
                    acc[mt][nt] = __builtin_amdgcn_mfma_f32_16x16x32_bf16(al[mt], bh[nt], acc[mt][nt], 0, 0, 0);
            #pragma unroll
            for (int mt = 0; mt < 4; ++mt)
                #pragma unroll
                for (int nt = 0; nt < NTW; ++nt)
                    acc[mt][nt] = __builtin_amdgcn_mfma_f32_16x16x32_bf16(ah[mt], bl[nt], acc[mt][nt], 0, 0, 0);
        }
    }

    // ---- epilogue: LDS transpose, full-sector coalesced stores ----
    const float av = alpha[0];
    u32* s_t = (u32*)s_a;                   // [256 px][stride 34] u32
    __syncthreads();
    #pragma unroll 1
    for (int pp = 0; pp < COUT / 32; ++pp) {
        if (pp) __syncthreads();
        #pragma unroll
        for (int nn = 0; nn < 2; ++nn) {
            const int nt = pp * 2 + nn;
            const float bs = bias[nt * 16 + ln];
            #pragma unroll
            for (int mt = 0; mt < 4; ++mt)
                #pragma unroll
                for (int reg = 0; reg < 4; ++reg) {
                    float t = acc[mt][nt][reg] + bs;
                    t = t > 0.f ? t : av * t;
                    u16 h = f2bf(t);
                    u16 l = f2bf(t - bf2f(h));
                    const int tp = w * 64 + mt * 16 + quad * 4 + reg;
                    s_t[tp * 34 + nn * 16 + ln] = (u32)h | ((u32)l << 16);
                }
        }
        __syncthreads();
        // store: 4 lanes per pixel (cw = 16-B chunk) -> full 64-B sectors
        const int cw = tid & 3;
        #pragma unroll
        for (int it = 0; it < 4; ++it) {
            const int px = (tid >> 2) + it * 64;
            const int r = px >> 6, c = px & 63;
            const u32* rowp = s_t + px * 34 + cw * 8;
            uint2 a0 = *(const uint2*)(rowp);
            uint2 a1 = *(const uint2*)(rowp + 2);
            uint2 a2 = *(const uint2*)(rowp + 4);
            uint2 a3 = *(const uint2*)(rowp + 6);
            uint4 hq, lq;
            hq.x = (a0.x & 0xffffu) | (a0.y << 16);
            hq.y = (a1.x & 0xffffu) | (a1.y << 16);
            hq.z = (a2.x & 0xffffu) | (a2.y << 16);
            hq.w = (a3.x & 0xffffu) | (a3.y << 16);
            lq.x = (a0.x >> 16) | (a0.y & 0xffff0000u);
            lq.y = (a1.x >> 16) | (a1.y & 0xffff0000u);
            lq.z = (a2.x >> 16) | (a2.y & 0xffff0000u);
            lq.w = (a3.x >> 16) | (a3.y & 0xffff0000u);
            const size_t gb = ((size_t)(y0 + r + 1) * PW + (x1 + c + 1)) * COUT
                            + pp * 32 + cw * 8;
            *(uint4*)(outh + gb) = hq;
            *(uint4*)(outl + gb) = lq;
        }
    }
}

// ---------------------------------------------------------------------------
// Head conv 32 -> 16 co (12 valid): async-staged MFMA + GAP atomics.
// Writes h as fp16 [head][b][px][4] (8B/px vector stores via LDS transpose).
// ---------------------------------------------------------------------------
__global__ __launch_bounds__(256, 3)
void head_mfma(const u16* __restrict__ inh, const u16* __restrict__ inl,
               const u16* __restrict__ wh, const u16* __restrict__ wl,
               const float* __restrict__ hb,
               __half* __restrict__ hbuf, float* __restrict__ g2, int b)
{
    constexpr int RSTR = 68 * 32;
    constexpr int PL   = 6 * RSTR;
    __shared__ __align__(16) u16 s_a[2 * PL];
    __shared__ float s_red[4][16];

    const int tid  = threadIdx.x;
    const int w    = tid >> 6;
    const int lane = tid & 63;
    const int ln   = lane & 15;
    const int quad = lane >> 4;
    const int x1   = blockIdx.x * 64;
    const int y0   = blockIdx.y * 4;
    const int px_off = lane >> 2;
    const int ci_off = (lane & 3) * 8;

    f32x4 acc[4];
    #pragma unroll
    for (int mt = 0; mt < 4; ++mt) acc[mt] = (f32x4){0.f, 0.f, 0.f, 0.f};

    for (int u = w; u < 12; u += 4) {
        const int r = u >> 1, p = u & 1;
        const u16* g = (p ? inl : inh) + ((size_t)(y0 + r) * PW + x1) * 32 + ci_off;
        u16* lb = s_a + p * PL + r * RSTR;
        #pragma unroll
        for (int j = 0; j < 4; ++j)
            __builtin_amdgcn_global_load_lds(
                (const void*)(g + (size_t)(j * 16 + px_off) * 32),
                (void*)(lb + j * 512), 16, 0, 0);
        if (lane < 16)
            __builtin_amdgcn_global_load_lds(
                (const void*)(g + (size_t)(64 + px_off) * 32),
                (void*)(lb + 4 * 512), 16, 0, 0);
    }
    __syncthreads();

    #pragma unroll
    for (int tap = 0; tap < 9; ++tap) {
        const int dy = tap / 3, dx = tap % 3;
        const size_t boff = (size_t)tap * 512 + ln * 32 + quad * 8;
        short8 bh = *(const short8*)(wh + boff);
        short8 bl = *(const short8*)(wl + boff);
        short8 ah[4], al[4];
        #pragma unroll
        for (int mt = 0; mt < 4; ++mt) {
            const int off = (w + dy) * RSTR + (mt * 16 + ln + dx) * 32 + quad * 8;
            ah[mt] = *(const short8*)(s_a + off);
            al[mt] = *(const short8*)(s_a + PL + off);
        }
        #pragma unroll
        for (int mt = 0; mt < 4; ++mt)
            acc[mt] = __builtin_amdgcn_mfma_f32_16x16x32_bf16(ah[mt], bh, acc[mt], 0, 0, 0);
        #pragma unroll
        for (int mt = 0; mt < 4; ++mt)
            acc[mt] = __builtin_amdgcn_mfma_f32_16x16x32_bf16(al[mt], bh, acc[mt], 0, 0, 0);
        #pragma unroll
        for (int mt = 0; mt < 4; ++mt)
            acc[mt] = __builtin_amdgcn_mfma_f32_16x16x32_bf16(ah[mt], bl, acc[mt], 0, 0, 0);
    }

    __syncthreads();                       // done reading s_a; reuse as f32 scratch
    float* s_hf = (float*)s_a;             // [256 px][stride 20] floats
    const float bs = hb[ln];
    float psum = 0.f;
    #pragma unroll
    for (int mt = 0; mt < 4; ++mt) {
        #pragma unroll
        for (int reg = 0; reg < 4; ++reg) {
            float v = acc[mt][reg] + bs;
            const int tp = w * 64 + mt * 16 + quad * 4 + reg;
            if (ln < 12) s_hf[tp * 20 + ln] = v;
            psum += v;                     // co >= 12: zero weights+bias -> 0
        }
    }
    psum += __shfl_down(psum, 16);
    psum += __shfl_down(psum, 32);
    if (lane < 16) s_red[w][lane] = psum;
    __syncthreads();

    {
        const int r = tid >> 6, c = tid & 63;
        const float* src = s_hf + tid * 20;
        float4 v0 = *(const float4*)(src);
        float4 v1 = *(const float4*)(src + 4);
        float4 v2 = *(const float4*)(src + 8);
        const size_t gpx = (size_t)(y0 + r) * 512 + x1 + c;
        float vv[12] = {v0.x, v0.y, v0.z, v0.w, v1.x, v1.y, v1.z, v1.w,
                        v2.x, v2.y, v2.z, v2.w};
        #pragma unroll
        for (int hd = 0; hd < 3; ++hd) {
            ushort4 u;
            u.x = __half_as_ushort(__float2half_rn(vv[hd * 4 + 0]));
            u.y = __half_as_ushort(__float2half_rn(vv[hd * 4 + 1]));
            u.z = __half_as_ushort(__float2half_rn(vv[hd * 4 + 2]));
            u.w = __half_as_ushort(__float2half_rn(vv[hd * 4 + 3]));
            *(ushort4*)((u16*)hbuf + ((size_t)(hd * 8 + b) * HWSZ + gpx) * 4) = u;
        }
    }
    if (tid < 12) {
        float t = s_red[0][tid] + s_red[1][tid] + s_red[2][tid] + s_red[3][tid];
        atomicAdd(&g2[(tid >> 2) * 32 + b * 4 + (tid & 3)], t);
    }
}

// ---------------------------------------------------------------------------
// conv1: 3 -> 32, fp32 direct, thread-per-pixel; LDS transpose epilogue with
// full-sector coalesced split-plane stores.
// ---------------------------------------------------------------------------
__global__ __launch_bounds__(256)
void conv1_pad(const float* __restrict__ x, const float* __restrict__ wgt,
               const float* __restrict__ bias, const float* __restrict__ alpha,
               u16* __restrict__ outh, u16* __restrict__ outl)
{
    __shared__ float s_in[3][6][72];
    __shared__ float s_w[3][9][32];
    __shared__ float s_b[32];
    __shared__ u32 s_t1[256 * 33];         // 33,792 B
    const int tid = threadIdx.x;
    const int x1 = blockIdx.x * 64, y0 = blockIdx.y * 4;

    for (int i = tid; i < 3 * 6 * 66; i += 256) {
        int ci = i / 396, rm = i % 396;
        int r = rm / 66, cc = rm % 66;
        int gy = y0 - 1 + r, gx = x1 - 1 + cc;
        float v = 0.f;
        if ((unsigned)gy < 512u && (unsigned)gx < 512u)
            v = x[(size_t)ci * HWSZ + gy * 512 + gx];
        s_in[ci][r][cc] = v;
    }
    for (int i = tid; i < 864; i += 256) {
        int co = i & 31, rm = i >> 5;
        int ci = rm / 9, tap = rm % 9;
        s_w[ci][tap][co] = wgt[(co * 3 + ci) * 9 + tap];
    }
    if (tid < 32) s_b[tid] = bias[tid];
    __syncthreads();

    const int ty = tid >> 6, tx = tid & 63;
    float acc[32];
    #pragma unroll
    for (int i = 0; i < 32; ++i) acc[i] = 0.f;
    #pragma unroll
    for (int ci = 0; ci < 3; ++ci)
        #pragma unroll
        for (int tap = 0; tap < 9; ++tap) {
            const int dy = tap / 3, dx = tap % 3;
            float iv = s_in[ci][ty + dy][tx + dx];
            #pragma unroll
            for (int c4 = 0; c4 < 8; ++c4) {
                float4 wv = *(const float4*)&s_w[ci][tap][c4 * 4];
                acc[c4*4+0] = fmaf(iv, wv.x, acc[c4*4+0]);
                acc[c4*4+1] = fmaf(iv, wv.y, acc[c4*4+1]);
                acc[c4*4+2] = fmaf(iv, wv.z, acc[c4*4+2]);
                acc[c4*4+3] = fmaf(iv, wv.w, acc[c4*4+3]);
            }
        }
    const float av = alpha[0];
    #pragma unroll
    for (int ch = 0; ch < 32; ++ch) {
        float t = acc[ch] + s_b[ch];
        t = t > 0.f ? t : av * t;
        u16 hh = f2bf(t);
        u16 ll = f2bf(t - bf2f(hh));
        s_t1[tid * 33 + ch] = (u32)hh | ((u32)ll << 16);
    }
    __syncthreads();
    const int cw = tid & 3;
    #pragma unroll
    for (int it = 0; it < 4; ++it) {
        const int px = (tid >> 2) + it * 64;
        const int r = px >> 6, c = px & 63;
        const u32* rowp = s_t1 + px * 33 + cw * 8;
        uint2 a0 = *(const uint2*)(rowp);
        uint2 a1 = *(const uint2*)(rowp + 2);
        uint2 a2 = *(const uint2*)(rowp + 4);
        uint2 a3 = *(const uint2*)(rowp + 6);
        uint4 hq, lq;
        hq.x = (a0.x & 0xffffu) | (a0.y << 16);
        hq.y = (a1.x & 0xffffu) | (a1.y << 16);
        hq.z = (a2.x & 0xffffu) | (a2.y << 16);
        hq.w = (a3.x & 0xffffu) | (a3.y << 16);
        lq.x = (a0.x >> 16) | (a0.y & 0xffff0000u);
        lq.y = (a1.x >> 16) | (a1.y & 0xffff0000u);
        lq.z = (a2.x >> 16) | (a2.y & 0xffff0000u);
        lq.w = (a3.x >> 16) | (a3.y & 0xffff0000u);
        const size_t gb = ((size_t)(y0 + r + 1) * PW + (x1 + c + 1)) * 32 + cw * 8;
        *(uint4*)(outh + gb) = hq;
        *(uint4*)(outl + gb) = lq;
    }
}

// ---------------------------------------------------------------------------
__global__ void zero_k(float* p, int n)
{
    int i = blockIdx.x * 256 + threadIdx.x;
    if (i < n) p[i] = 0.f;
}

__global__ void ca_kernel(const float* __restrict__ g,
                          const float* __restrict__ c11, const float* __restrict__ c12,
                          const float* __restrict__ c21, const float* __restrict__ c22,
                          const float* __restrict__ c31, const float* __restrict__ c32,
                          float* __restrict__ sOut)
{
    int t = threadIdx.x;
    if (t >= 24) return;
    int head = t / 8, b = t % 8;
    const float* c1 = head == 0 ? c11 : (head == 1 ? c21 : c31);
    const float* c2 = head == 0 ? c12 : (head == 1 ? c22 : c32);
    float m[4], v[4];
    #pragma unroll
    for (int i = 0; i < 4; ++i) m[i] = g[head * 32 + b * 4 + i] * (1.0f / 262144.0f);
    #pragma unroll
    for (int j = 0; j < 4; ++j) {
        float xv = c1[j*4+0]*m[0] + c1[j*4+1]*m[1] + c1[j*4+2]*m[2] + c1[j*4+3]*m[3];
        v[j] = fmaxf(xv, 0.f);
    }
    #pragma unroll
    for (int j = 0; j < 4; ++j) {
        float xv = c2[j*4+0]*v[0] + c2[j*4+1]*v[1] + c2[j*4+2]*v[2] + c2[j*4+3]*v[3];
        sOut[head * 32 + b * 4 + j] = 1.f / (1.f + __expf(-xv));
    }
}

// ---------------------------------------------------------------------------
// Integral image (SAT): 513x513 per (b,c) plane.
// ---------------------------------------------------------------------------
__global__ __launch_bounds__(256)
void sat_row(const float* __restrict__ src, float* __restrict__ S)
{
    const int y  = blockIdx.x;
    const int bc = blockIdx.y;
    float* Sp = S + (size_t)bc * 263169;
    const int tid = threadIdx.x;
    if (y == 0) {
        for (int i = tid; i < 513; i += 256) Sp[i] = 0.f;
        return;
    }
    const float2* row2 = (const float2*)(src + (size_t)bc * HWSZ + (size_t)(y - 1) * 512);
    float2 ab = row2[tid];
    float ps = ab.x + ab.y;
    float v = ps;
    const int lane = tid & 63;
    #pragma unroll
    for (int off = 1; off < 64; off <<= 1) {
        float u = __shfl_up(v, off);
        if (lane >= off) v += u;
    }
    __shared__ float wsum[4];
    const int wv = tid >> 6;
    if (lane == 63) wsum[wv] = v;
    __syncthreads();
    float woff = 0.f;
    #pragma unroll
    for (int k = 0; k < 4; ++k) if (k < wv) woff += wsum[k];
    float excl = woff + v - ps;
    float* o = Sp + (size_t)y * 513;
    if (tid == 0) o[0] = 0.f;
    o[1 + 2 * tid] = excl + ab.x;
    o[2 + 2 * tid] = excl + ab.x + ab.y;
}

__global__ __launch_bounds__(256)
void sat_col(float* __restrict__ S)
{
    const int bc = blockIdx.x;
    const int c  = 1 + blockIdx.y * 256 + threadIdx.x;
    float* P = S + (size_t)bc * 263169 + c;
    float run = 0.f;
    for (int r0 = 1; r0 <= 512; r0 += 16) {
        float v[16];
        #pragma unroll
        for (int i = 0; i < 16; ++i) v[i] = P[(size_t)(r0 + i) * 513];
        #pragma unroll
        for (int i = 0; i < 16; ++i) { run += v[i]; v[i] = run; }
        #pragma unroll
        for (int i = 0; i < 16; ++i) P[(size_t)(r0 + i) * 513] = v[i];
    }
}

__device__ __forceinline__ float boxsum(const float* __restrict__ S, int y, int x, int p)
{
    int y0 = max(y - p, 0), x0 = max(x - p, 0);
    int y1 = min(y + p, 511) + 1, x1 = min(x + p, 511) + 1;
    return S[y1 * 513 + x1] - S[y0 * 513 + x1] - S[y1 * 513 + x0] + S[y0 * 513 + x0];
}

__global__ __launch_bounds__(256)
void fuse_kernel(const float* __restrict__ cur, const __half* __restrict__ h,
                 const float* __restrict__ sv, const float* __restrict__ S,
                 float* __restrict__ out, int head)
{
    const int idx = blockIdx.x * 256 + threadIdx.x;
    const int b   = idx >> 18;
    const int rem = idx & 262143;
    const int y   = rem >> 9;
    const int x   = rem & 511;

    const float* sp = sv + head * 32 + b * 4;
    const __half* hp = h + ((size_t)(head * 8 + b) * HWSZ + rem) * 4;
    float z0 = __half2float(hp[0]) * sp[0];
    float z1 = __half2float(hp[1]) * sp[1];
    float z2 = __half2float(hp[2]) * sp[2];
    float z3 = __half2float(hp[3]) * sp[3];
    float m  = fmaxf(fmaxf(z0, z1), fmaxf(z2, z3));
    float e0 = __expf(z0 - m), e1 = __expf(z1 - m), e2 = __expf(z2 - m), e3 = __expf(z3 - m);
    float inv = 1.f / (e0 + e1 + e2 + e3);
    float p0 = e0 * inv, p1 = e1 * inv, p2 = e2 * inv, p3 = e3 * inv;

    #pragma unroll
    for (int c = 0; c < 3; ++c) {
        const float* Sp = S + (size_t)(b * 3 + c) * 263169;
        float xv = cur[((size_t)b * 3 + c) * HWSZ + rem];
        float m2 = boxsum(Sp, y, x, 2)  * (1.f / 25.f);
        float m3 = boxsum(Sp, y, x, 7)  * (1.f / 225.f);
        float m4 = boxsum(Sp, y, x, 12) * (1.f / 625.f);
        out[((size_t)b * 3 + c) * HWSZ + rem] = p0 * xv + p1 * m2 + p2 * m3 + p3 * m4;
    }
}

// ---------------------------------------------------------------------------
// Workspace (u16 units):
//   t1h/t1l: 8,487,168 each   (514x516x32 padded bf16 planes)
//   t2h/t2l: 16,974,336 each  (514x516x64)
//   hbuf: 25,165,824 halfs    ([3 heads][8 b][HW][4 ch] fp16)
//   gbuf/sbuf/weights: small.  Total ~152.5 MB. SAT aliases t2, ping aliases t1.
// ---------------------------------------------------------------------------
extern "C" void kernel_launch(void* const* d_in, const int* in_sizes, int n_in,
                              void* d_out, int out_size, void* d_ws, size_t ws_size,
                              hipStream_t stream)
{
    (void)in_sizes; (void)n_in; (void)out_size; (void)ws_size;
    const float* x    = (const float*)d_in[0];
    const float* bw1  = (const float*)d_in[1];
    const float* bb1  = (const float*)d_in[2];
    const float* a1   = (const float*)d_in[3];
    const float* bw2  = (const float*)d_in[4];
    const float* bb2  = (const float*)d_in[5];
    const float* a2   = (const float*)d_in[6];
    const float* bw3  = (const float*)d_in[7];
    const float* bb3  = (const float*)d_in[8];
    const float* a3   = (const float*)d_in[9];
    const float* h1w  = (const float*)d_in[10];
    const float* h1b  = (const float*)d_in[11];
    const float* h1c1 = (const float*)d_in[12];
    const float* h1c2 = (const float*)d_in[13];
    const float* h2w  = (const float*)d_in[14];
    const float* h2b  = (const float*)d_in[15];
    const float* h2c1 = (const float*)d_in[16];
    const float* h2c2 = (const float*)d_in[17];
    const float* h3w  = (const float*)d_in[18];
    const float* h3b  = (const float*)d_in[19];
    const float* h3c1 = (const float*)d_in[20];
    const float* h3c2 = (const float*)d_in[21];

    u16* b16 = (u16*)d_ws;
    const size_t T1P = (size_t)PH * PW * 32;   // 8,487,168
    const size_t T2P = (size_t)PH * PW * 64;   // 16,974,336
    u16* t1h = b16;
    u16* t1l = t1h + T1P;
    u16* t2h = t1l + T1P;
    u16* t2l = t2h + T2P;
    __half* hbuf = (__half*)(t2l + T2P);
    float* gbuf = (float*)((u16*)hbuf + 25165824);
    float* sbuf = gbuf + 96;
    u16* wb  = (u16*)(sbuf + 96);
    u16* w2h = wb;
    u16* w2l = wb + 18432;
    u16* w3h = wb + 36864;
    u16* w3l = wb + 55296;
    u16* whh = wb + 73728;
    u16* whl = wb + 78336;
    float* hb16 = (float*)(wb + 82944);
    float* SAT  = (float*)t2h;          // t2 dead after batch loop
    float* ping = (float*)t1h;          // t1 dead after batch loop

    dim3 blk(256);
    dim3 cg(8, 128);

    prep_weights<<<dim3(163), blk, 0, stream>>>(bw2, bw3, h1w, h2w, h3w,
                                                h1b, h2b, h3b,
                                                w2h, w2l, w3h, w3l, whh, whl, hb16);
    zero_pads<<<dim3(9, 4), blk, 0, stream>>>(t1h, t1l, t2h, t2l);
    zero_k<<<dim3(1), dim3(128), 0, stream>>>(gbuf, 96);

    // per-batch body: x[b] -> t1 -> t2 -> t1 -> heads
    for (int b = 0; b < 8; ++b) {
        conv1_pad<<<cg, blk, 0, stream>>>(x + (size_t)b * 3 * HWSZ,
                                          bw1, bb1, a1, t1h, t1l);
        conv_mfma<32, 64><<<cg, blk, 0, stream>>>(t1h, t1l, w2h, w2l, bb2, a2, t2h, t2l);
        conv_mfma<64, 32><<<cg, blk, 0, stream>>>(t2h, t2l, w3h, w3l, bb3, a3, t1h, t1l);
        head_mfma<<<cg, blk, 0, stream>>>(t1h, t1l, whh, whl, hb16, hbuf, gbuf, b);
    }

    ca_kernel<<<dim3(1), dim3(64), 0, stream>>>(gbuf, h1c1, h1c2, h2c1, h2c2,
                                                h3c1, h3c2, sbuf);

    // fuse chain: x -> ping -> ping(in place) -> d_out
    const float* cur = x;
    for (int i = 0; i < 3; ++i) {
        sat_row<<<dim3(513, 24), blk, 0, stream>>>(cur, SAT);
        sat_col<<<dim3(24, 2), blk, 0, stream>>>(SAT);
        float* nxt = (i == 2) ? (float*)d_out : ping;
        fuse_kernel<<<dim3(8192), blk, 0, stream>>>(cur, hbuf, sbuf, SAT, nxt, i);
        cur = nxt;
    }
}